// Round 5
// baseline (720.012 us; speedup 1.0000x reference)
//
#include <hip/hip_runtime.h>
#include <math.h>

#define NROWS 65536
#define DFULL 512
#define HHEADS 8
#define KCODES 512
#define HDIM 64

// ws layout (bytes):
//   [0, 8)         double loss_sum
//   [64, +16384)   u32 hist[H*K]
//   [32768, +16KB) float t3[H*K]  (XLA-strict sequential f32 ||c||^2)
#define WS_LOSS 0
#define WS_HIST 64
#define WS_T3   32768

// XLA:CPU strict-FP reduce: sequential ascending f32 adds (no reassociation).
__device__ __forceinline__ float seq_sumsq64(const float* x) {
    float s = __fmul_rn(x[0], x[0]);
    #pragma unroll
    for (int i = 1; i < 64; ++i) s = __fadd_rn(s, __fmul_rn(x[i], x[i]));
    return s;
}

// Eigen/oneDNN sgemm inner product: k-ascending sequential f32 FMA, acc=0.
__device__ __forceinline__ float seq_fma_dot64(const float* zf,
                                               const float* __restrict__ cf) {
    float acc = 0.0f;
    #pragma unroll
    for (int d = 0; d < 64; ++d) acc = __fmaf_rn(zf[d], cf[d], acc);
    return acc;
}

__global__ void vq_prep_t3(const float* __restrict__ cb, float* __restrict__ t3) {
    int row = blockIdx.x * blockDim.x + threadIdx.x;  // one thread per (h,k)
    if (row >= HHEADS * KCODES) return;
    const float* c = cb + (size_t)row * HDIM;
    float cl[64];
    #pragma unroll
    for (int i = 0; i < 64; ++i) cl[i] = c[i];
    t3[row] = seq_sumsq64(cl);
}

__global__ __launch_bounds__(64) void vq_main(
    const float* __restrict__ z_e, const float* __restrict__ cb,
    const float* __restrict__ t3,
    float* __restrict__ out, double* __restrict__ loss_sum,
    unsigned* __restrict__ hist) {
    const int lane = threadIdx.x;
    const int bid = blockIdx.x;             // 8192 blocks = (N/64) * H
    const int h = bid & 7;
    const int rowblk = bid >> 3;
    const size_t rowbase = (size_t)rowblk * 64;
    const size_t myrow = rowbase + lane;

    // Load my row's head-slice.
    float zf[HDIM];
    const float* zp = z_e + myrow * DFULL + (size_t)h * HDIM;
    #pragma unroll
    for (int d4 = 0; d4 < HDIM; d4 += 4) {
        float4 v = *(const float4*)(zp + d4);
        zf[d4 + 0] = v.x; zf[d4 + 1] = v.y; zf[d4 + 2] = v.z; zf[d4 + 3] = v.w;
    }

    // t1 = strict sequential sum of f32 squares (XLA:CPU reduce, fast-math off).
    const float t1 = seq_sumsq64(zf);

    const float* cbh = cb + (size_t)(h * KCODES) * HDIM;
    const float* t3h = t3 + (size_t)h * KCODES;

    float best = INFINITY;
    int bestk = 0;
    // 4-way k-interleave for ILP; per-k arithmetic is bitwise order-invariant.
    for (int k = 0; k < KCODES; k += 4) {
        const float* c0 = cbh + (size_t)(k + 0) * HDIM;
        const float* c1 = cbh + (size_t)(k + 1) * HDIM;
        const float* c2 = cbh + (size_t)(k + 2) * HDIM;
        const float* c3 = cbh + (size_t)(k + 3) * HDIM;
        float a0 = 0.0f, a1 = 0.0f, a2 = 0.0f, a3 = 0.0f;
        #pragma unroll
        for (int d = 0; d < 64; ++d) {
            a0 = __fmaf_rn(zf[d], c0[d], a0);
            a1 = __fmaf_rn(zf[d], c1[d], a1);
            a2 = __fmaf_rn(zf[d], c2[d], a2);
            a3 = __fmaf_rn(zf[d], c3[d], a3);
        }
        // d = (t1 - 2*t2) + t3, each op f32-rounded (2*t2 exact).
        float d0 = __fadd_rn(__fsub_rn(t1, __fmul_rn(2.0f, a0)), t3h[k + 0]);
        float d1 = __fadd_rn(__fsub_rn(t1, __fmul_rn(2.0f, a1)), t3h[k + 1]);
        float d2 = __fadd_rn(__fsub_rn(t1, __fmul_rn(2.0f, a2)), t3h[k + 2]);
        float d3 = __fadd_rn(__fsub_rn(t1, __fmul_rn(2.0f, a3)), t3h[k + 3]);
        // strict < with ascending k preserves first-index tie-break.
        if (d0 < best) { best = d0; bestk = k + 0; }
        if (d1 < best) { best = d1; bestk = k + 1; }
        if (d2 < best) { best = d2; bestk = k + 2; }
        if (d3 < best) { best = d3; bestk = k + 3; }
    }

    // idx output (as float in the concatenated f32 out buffer)
    out[(size_t)NROWS * DFULL + myrow * HHEADS + h] = (float)bestk;
    atomicAdd(&hist[h * KCODES + bestk], 1u);

    // Cooperative gather: broadcast each lane's idx, coalesced 256B rows.
    double lsum = 0.0;
    for (int r = 0; r < 64; ++r) {
        int ir = __shfl(bestk, r, 64);
        float cv = cbh[(size_t)ir * HDIM + lane];
        size_t row = rowbase + r;
        float ze = z_e[row * DFULL + (size_t)h * HDIM + lane];
        float diff = cv - ze;
        out[row * DFULL + (size_t)h * HDIM + lane] = ze + diff; // z_e + (z_q - z_e)
        lsum += (double)diff * (double)diff;
    }
    #pragma unroll
    for (int off = 32; off; off >>= 1) lsum += __shfl_xor(lsum, off, 64);
    if (lane == 0) atomicAdd(loss_sum, lsum);
}

__global__ void vq_final(const unsigned* __restrict__ hist,
                         const double* __restrict__ loss_sum,
                         float* __restrict__ out) {
    const int tid = threadIdx.x;
    const int wave = tid >> 6;  // 8 waves, one per head
    const int lane = tid & 63;
    __shared__ double perp[HHEADS];
    double e = 0.0;
    for (int k = lane; k < KCODES; k += 64) {
        double p = (double)hist[wave * KCODES + k] / (double)NROWS;
        e += p * log(p + 1e-10);
    }
    #pragma unroll
    for (int off = 32; off; off >>= 1) e += __shfl_xor(e, off, 64);
    if (lane == 0) perp[wave] = exp(-e);
    __syncthreads();
    if (tid == 0) {
        double m = 0.0;
        #pragma unroll
        for (int i = 0; i < HHEADS; ++i) m += perp[i];
        m /= (double)HHEADS;
        double S = *loss_sum;
        double cl = S / ((double)NROWS * (double)DFULL);
        size_t base = (size_t)NROWS * DFULL + (size_t)NROWS * HHEADS;
        out[base + 0] = (float)cl;
        out[base + 1] = (float)(0.1 * cl);
        out[base + 2] = (float)m;
    }
}

extern "C" void kernel_launch(void* const* d_in, const int* in_sizes, int n_in,
                              void* d_out, int out_size, void* d_ws, size_t ws_size,
                              hipStream_t stream) {
    const float* z_e = (const float*)d_in[0];
    const float* cb  = (const float*)d_in[1];
    float* out = (float*)d_out;
    char* ws = (char*)d_ws;
    double* loss   = (double*)(ws + WS_LOSS);
    unsigned* hist = (unsigned*)(ws + WS_HIST);
    float* t3      = (float*)(ws + WS_T3);

    hipMemsetAsync(ws, 0, WS_HIST + (size_t)HHEADS * KCODES * 4, stream);

    vq_prep_t3<<<dim3((HHEADS * KCODES + 255) / 256), dim3(256), 0, stream>>>(cb, t3);

    vq_main<<<dim3((NROWS / 64) * HHEADS), dim3(64), 0, stream>>>(
        z_e, cb, t3, out, loss, hist);

    vq_final<<<dim3(1), dim3(512), 0, stream>>>(hist, loss, out);
}

// Round 6
// 571.041 us; speedup vs baseline: 1.2609x; 1.2609x over previous
//
#include <hip/hip_runtime.h>
#include <math.h>

#define NROWS 65536
#define DFULL 512
#define HHEADS 8
#define KCODES 512
#define HDIM 64

// ws layout (bytes):
//   [0, 8)         double loss_sum
//   [64, +16384)   u32 hist[H*K]
//   [32768, +16KB) float t3[H*K]  (XLA-strict sequential f32 ||c||^2)
#define WS_LOSS 0
#define WS_HIST 64
#define WS_T3   32768

// XLA:CPU strict-FP reduce: sequential ascending f32 adds (no reassociation).
__device__ __forceinline__ float seq_sumsq64(const float* x) {
    float s = __fmul_rn(x[0], x[0]);
    #pragma unroll
    for (int i = 1; i < 64; ++i) s = __fadd_rn(s, __fmul_rn(x[i], x[i]));
    return s;
}

__global__ void vq_prep_t3(const float* __restrict__ cb, float* __restrict__ t3) {
    int row = blockIdx.x * blockDim.x + threadIdx.x;  // one thread per (h,k)
    if (row >= HHEADS * KCODES) return;
    const float* c = cb + (size_t)row * HDIM;
    float cl[64];
    #pragma unroll
    for (int i = 0; i < 64; ++i) cl[i] = c[i];
    t3[row] = seq_sumsq64(cl);
}

// Block = 256 threads = 4 waves, ALL on the same head (block-uniform h so the
// codebook pointer is provably scalar -> s_load stream on the SMEM pipe).
// Each wave owns one 64-row block; per-wave arithmetic is bitwise identical
// to the round-5 passing kernel.
__global__ __launch_bounds__(256, 4) void vq_main(
    const float* __restrict__ z_e, const float* __restrict__ cb,
    const float* __restrict__ t3,
    float* __restrict__ out, double* __restrict__ loss_sum,
    unsigned* __restrict__ hist) {
    const int lane = threadIdx.x & 63;
    const int wv   = threadIdx.x >> 6;
    const int h    = blockIdx.x & 7;                   // block-uniform
    const int rowblk = (blockIdx.x >> 3) * 4 + wv;     // wave-uniform
    const size_t rowbase = (size_t)rowblk * 64;
    const size_t myrow = rowbase + lane;

    // Load my row's head-slice and PIN it in VGPRs (identity asm prevents
    // the compiler from rematerializing these as per-iteration L1 re-loads).
    float zf[HDIM];
    const float* zp = z_e + myrow * DFULL + (size_t)h * HDIM;
    #pragma unroll
    for (int d4 = 0; d4 < HDIM; d4 += 4) {
        float4 v = *(const float4*)(zp + d4);
        zf[d4 + 0] = v.x; zf[d4 + 1] = v.y; zf[d4 + 2] = v.z; zf[d4 + 3] = v.w;
    }
    #pragma unroll
    for (int i = 0; i < HDIM; ++i) asm volatile("" : "+v"(zf[i]));

    // t1 = strict sequential sum of f32 squares (XLA:CPU reduce, fast-math off).
    const float t1 = seq_sumsq64(zf);

    const float* cbh = cb + (size_t)(h * KCODES) * HDIM;
    const float* t3h = t3 + (size_t)h * KCODES;

    float best = INFINITY;
    int bestk = 0;
    // 4-way k-interleave for ILP; per-k arithmetic is bitwise order-invariant.
    for (int k = 0; k < KCODES; k += 4) {
        const float* c0 = cbh + (size_t)(k + 0) * HDIM;
        const float* c1 = cbh + (size_t)(k + 1) * HDIM;
        const float* c2 = cbh + (size_t)(k + 2) * HDIM;
        const float* c3 = cbh + (size_t)(k + 3) * HDIM;
        float a0 = 0.0f, a1 = 0.0f, a2 = 0.0f, a3 = 0.0f;
        #pragma unroll
        for (int d = 0; d < 64; ++d) {
            a0 = __fmaf_rn(zf[d], c0[d], a0);
            a1 = __fmaf_rn(zf[d], c1[d], a1);
            a2 = __fmaf_rn(zf[d], c2[d], a2);
            a3 = __fmaf_rn(zf[d], c3[d], a3);
        }
        // d = (t1 - 2*t2) + t3, each op f32-rounded (2*t2 exact).
        float d0 = __fadd_rn(__fsub_rn(t1, __fmul_rn(2.0f, a0)), t3h[k + 0]);
        float d1 = __fadd_rn(__fsub_rn(t1, __fmul_rn(2.0f, a1)), t3h[k + 1]);
        float d2 = __fadd_rn(__fsub_rn(t1, __fmul_rn(2.0f, a2)), t3h[k + 2]);
        float d3 = __fadd_rn(__fsub_rn(t1, __fmul_rn(2.0f, a3)), t3h[k + 3]);
        // strict < with ascending k preserves first-index tie-break.
        if (d0 < best) { best = d0; bestk = k + 0; }
        if (d1 < best) { best = d1; bestk = k + 1; }
        if (d2 < best) { best = d2; bestk = k + 2; }
        if (d3 < best) { best = d3; bestk = k + 3; }
    }

    // idx output (as float in the concatenated f32 out buffer)
    out[(size_t)NROWS * DFULL + myrow * HHEADS + h] = (float)bestk;
    atomicAdd(&hist[h * KCODES + bestk], 1u);

    // Cooperative gather: broadcast each lane's idx, coalesced 256B rows.
    double lsum = 0.0;
    for (int r = 0; r < 64; ++r) {
        int ir = __shfl(bestk, r, 64);
        float cv = cbh[(size_t)ir * HDIM + lane];
        size_t row = rowbase + r;
        float ze = z_e[row * DFULL + (size_t)h * HDIM + lane];
        float diff = cv - ze;
        out[row * DFULL + (size_t)h * HDIM + lane] = ze + diff; // z_e + (z_q - z_e)
        lsum += (double)diff * (double)diff;
    }
    #pragma unroll
    for (int off = 32; off; off >>= 1) lsum += __shfl_xor(lsum, off, 64);
    if (lane == 0) atomicAdd(loss_sum, lsum);
}

__global__ void vq_final(const unsigned* __restrict__ hist,
                         const double* __restrict__ loss_sum,
                         float* __restrict__ out) {
    const int tid = threadIdx.x;
    const int wave = tid >> 6;  // 8 waves, one per head
    const int lane = tid & 63;
    __shared__ double perp[HHEADS];
    double e = 0.0;
    for (int k = lane; k < KCODES; k += 64) {
        double p = (double)hist[wave * KCODES + k] / (double)NROWS;
        e += p * log(p + 1e-10);
    }
    #pragma unroll
    for (int off = 32; off; off >>= 1) e += __shfl_xor(e, off, 64);
    if (lane == 0) perp[wave] = exp(-e);
    __syncthreads();
    if (tid == 0) {
        double m = 0.0;
        #pragma unroll
        for (int i = 0; i < HHEADS; ++i) m += perp[i];
        m /= (double)HHEADS;
        double S = *loss_sum;
        double cl = S / ((double)NROWS * (double)DFULL);
        size_t base = (size_t)NROWS * DFULL + (size_t)NROWS * HHEADS;
        out[base + 0] = (float)cl;
        out[base + 1] = (float)(0.1 * cl);
        out[base + 2] = (float)m;
    }
}

extern "C" void kernel_launch(void* const* d_in, const int* in_sizes, int n_in,
                              void* d_out, int out_size, void* d_ws, size_t ws_size,
                              hipStream_t stream) {
    const float* z_e = (const float*)d_in[0];
    const float* cb  = (const float*)d_in[1];
    float* out = (float*)d_out;
    char* ws = (char*)d_ws;
    double* loss   = (double*)(ws + WS_LOSS);
    unsigned* hist = (unsigned*)(ws + WS_HIST);
    float* t3      = (float*)(ws + WS_T3);

    hipMemsetAsync(ws, 0, WS_HIST + (size_t)HHEADS * KCODES * 4, stream);

    vq_prep_t3<<<dim3((HHEADS * KCODES + 255) / 256), dim3(256), 0, stream>>>(cb, t3);

    // 2048 blocks x 256 threads: (rowblk_base, h) per block, 4 row-blocks/block
    vq_main<<<dim3((NROWS / 64 / 4) * HHEADS), dim3(256), 0, stream>>>(
        z_e, cb, t3, out, loss, hist);

    vq_final<<<dim3(1), dim3(512), 0, stream>>>(hist, loss, out);
}